// Round 8
// baseline (695.943 us; speedup 1.0000x reference)
//
#include <hip/hip_runtime.h>
#include <math.h>

#define NWAY 5
#define NSUP 25
#define NZV  125
#define DF   640
#define NQ   75
#define TPB  640   // two batches per block: waves 0-4 batch A, 5-9 batch B

// =====================================================================
// Fast transform: tf(x) = sign(x) * (g(|x|+1e-5) - g(1e-5)),
//   g(t) = ln(1/t+1)^{-1.3} = exp2(-1.3*log2(log2(1/t+1)) + A),
//   A = -1.3*log2(ln2) = 0.68739628. 4 transcendentals vs reference's 8.
// =====================================================================
__device__ __forceinline__ float gfun(float t) {
  const float l2 = __log2f(__builtin_amdgcn_rcpf(t) + 1.0f);
  return __builtin_amdgcn_exp2f(fmaf(-1.3f, __log2f(l2), 0.68739628f));
}
__device__ __forceinline__ float simple_tf(float x, float Cg) {
  const float s = gfun(fabsf(x) + 1e-5f) - Cg;
  return (x >= 0.0f) ? s : -s;
}

// Fast fp64 reciprocal: v_rcp_f64 + 2 Newton -> full fp64 accuracy
// (validated R2-R7: absmax bit-identical to exact divide). Inputs > 0.
__device__ __forceinline__ double fdrcp(double d) {
  double r;
  asm("v_rcp_f64 %0, %1" : "=v"(r) : "v"(d));
  r = r * fma(-d, r, 2.0);
  r = r * fma(-d, r, 2.0);
  return r;
}

// Constant-lane fp64 broadcast via v_readlane (VALU, off the LDS pipe).
__device__ __forceinline__ double bcastd(double v, const int srclane) {
  const int lo = __builtin_amdgcn_readlane(__double2loint(v), srclane);
  const int hi = __builtin_amdgcn_readlane(__double2hiint(v), srclane);
  return __hiloint2double(hi, lo);
}

// =====================================================================
// Per-half flag barrier: monotone LDS counter, 5 waves per half. All
// waves of a workgroup are gang-resident -> spin is deadlock-free.
// Producer: s_waitcnt lgkmcnt(0) drains this wave's LDS writes before
// signalling (all cross-thread QP state lives in LDS). Replaces
// __syncthreads so (a) the two halves' barrier schedules DECOUPLE --
// one batch's serial GJ/LDS latency chains overlap the other's stalls
// instead of all 10 waves idling in the same chain -- and (b) no
// vmcnt(0) full-drain is imposed per phase. NOTE: R3's apparent hbar
// regression is now attributed to its CHW=128 spill cliff (R3 vs R6 at
// equal spill traffic favors hbar 356 vs 586 us); this round tests
// hbar on the clean CHW=64 baseline, as the ONLY delta vs R5.
// =====================================================================
__device__ __forceinline__ void hbar(unsigned* c, unsigned& tgt,
                                     const int lane) {
  tgt += 5;
  asm volatile("s_waitcnt lgkmcnt(0)" ::: "memory");
  if (lane == 0)
    __hip_atomic_fetch_add(c, 1u, __ATOMIC_RELAXED,
                           __HIP_MEMORY_SCOPE_WORKGROUP);
  while (__hip_atomic_load(c, __ATOMIC_RELAXED,
                           __HIP_MEMORY_SCOPE_WORKGROUP) < tgt)
    __builtin_amdgcn_s_sleep(1);
  asm volatile("" ::: "memory");
}

// In-place Gauss-Jordan of 25x25 SPD; columns live on lanes BASE..BASE+24.
template <int BASE, int J>
__device__ __forceinline__ void gjp(double (&a)[25], const int lane,
                                    const bool act) {
  const double djj = bcastd(a[J], BASE + J);
  const double pinv = fdrcp(djj);
  if (act) a[J] = ((lane == BASE + J) ? 1.0 : a[J]) * pinv;
#pragma unroll
  for (int r = 0; r < 25; ++r) {
    if (r != J) {
      const double f = bcastd(a[r], BASE + J);
      if (act) a[r] = ((lane == BASE + J) ? 0.0 : a[r]) - f * a[J];
    }
  }
}
template <int BASE, int J = 0>
__device__ __forceinline__ void gjall(double (&a)[25], const int lane,
                                      const bool act) {
  if constexpr (J < 25) {
    gjp<BASE, J>(a, lane, act);
    gjall<BASE, J + 1>(a, lane, act);
  }
}

// Factorize (per half): hv <- row `lane` of Hinv_w; this half's wave-0
// lanes 32-56 additionally get Winv = (sum_k Hinv_k)^-1 rows.
// W accumulation: write-first sequential waves (R5 scheme -- the R7
// Hs-dump variant put a 5x-heavier gather on critical wave 0 and
// regressed; LDS atomics regressed R2).
__device__ __forceinline__ void factorize(const double* Msh, const double* dd,
                                          double* W, double (&hv)[25],
                                          const int tl, const int lane,
                                          const int w, unsigned* bc,
                                          unsigned& bt) {
  if (lane < 25) {
#pragma unroll
    for (int j = 0; j < 25; ++j)
      hv[j] = Msh[lane * 26 + j] + ((j == lane) ? dd[lane * 5 + w] : 0.0);
  }
  gjall<0>(hv, lane, true);
#pragma unroll
  for (int k = 0; k < 5; ++k) {
    if (w == k && lane < 25) {
      if (k == 0) {
#pragma unroll
        for (int j = 0; j < 25; ++j) W[lane * 26 + j] = hv[j];
      } else {
#pragma unroll
        for (int j = 0; j < 25; ++j) W[lane * 26 + j] += hv[j];
      }
    }
    hbar(bc, bt, lane);
  }
  if (w == 0) {
    if (lane >= 32 && lane < 57) {
#pragma unroll
      for (int r = 0; r < 25; ++r) hv[r] = W[(lane - 32) * 26 + r];
    }
    gjall<32>(hv, lane, lane >= 32 && lane < 57);
  }
  // next consumer phase begins with its own hbar
}

// KKT solve (per half). ZRS: rs==0; ZR: rx=rz=ry==0; ACC: accumulate.
// di = 1/dd precomputed -> the two per-solve divides become multiplies.
template <bool ZRS, bool ZR, bool ACC>
__device__ __forceinline__ void kkt_solve(
    const double* Msh, const double* dd, const double* di, double* tt,
    double* c1, double* c2, double* vv, double* gg, double* dyw,
    const double* rx, const double* rs, const double* rz, const double* ry,
    double (&hv)[25], double* dx, double* ds, double* dz, double* dy,
    const int tl, const int lane, const int w, unsigned* bc, unsigned& bt) {
  if (tl < NZV) {
    double t = ZR ? 0.0 : rz[tl];
    if (!ZRS) t -= rs[tl] * di[tl];
    tt[tl] = t;
  }
  hbar(bc, bt, lane);
  if (tl < NZV) {
    const int i = tl / 5, k = tl - i * 5;
    double acc = ZR ? 0.0 : -rx[tl];
#pragma unroll
    for (int j = 0; j < 25; ++j) acc += Msh[i * 26 + j] * tt[j * 5 + k];
    c1[tl] = acc;
  } else if (tl >= 128 && tl < 153) {
    const int i = tl - 128;
    double acc = ZR ? 0.0 : -ry[i];
#pragma unroll
    for (int k = 0; k < 5; ++k) acc += tt[i * 5 + k];
    c2[i] = acc;
  }
  hbar(bc, bt, lane);
  if (lane < 25) {
    double acc = 0.0;
#pragma unroll
    for (int j = 0; j < 25; ++j) acc += hv[j] * c1[j * 5 + w];
    vv[lane * 5 + w] = acc;
  }
  hbar(bc, bt, lane);
  if (w == 0) {  // gg then dy in the SAME wave: LDS program order suffices
    if (lane < 25) {
      double acc = -c2[lane];
#pragma unroll
      for (int k = 0; k < 5; ++k) acc += vv[lane * 5 + k];
      gg[lane] = acc;
    }
    if (lane >= 32 && lane < 57) {
      double acc = 0.0;
#pragma unroll
      for (int r = 0; r < 25; ++r) acc += hv[r] * gg[r];
      dyw[lane - 32] = acc;
      if (ACC) dy[lane - 32] += acc; else dy[lane - 32] = acc;
    }
  }
  hbar(bc, bt, lane);
  if (lane < 25) {
    double acc = 0.0;
#pragma unroll
    for (int j = 0; j < 25; ++j) acc += hv[j] * dyw[j];
    const int v = lane * 5 + w;
    const double u = vv[v] - acc;
    const double dzv = dd[v] * u;
    const double dxv = u - tt[v];
    const double dsv = ((ZRS ? 0.0 : -rs[v]) - dzv) * di[v];
    if (ACC) { dz[v] += dzv; dx[v] += dxv; ds[v] += dsv; }
    else     { dz[v]  = dzv; dx[v]  = dxv; ds[v]  = dsv; }
  }
  hbar(bc, bt, lane);
}

// Per-half block reduction: first wave of the half reduces buf[0..n).
__device__ __forceinline__ double bred(const double* buf, int n, int ismin,
                                       double* SCh, const int w,
                                       const int lane, unsigned* bc,
                                       unsigned& bt) {
  hbar(bc, bt, lane);
  if (w == 0) {
    double acc = ismin ? 1e300 : 0.0;
    for (int m = lane; m < n; m += 64) {
      const double v = buf[m];
      acc = ismin ? fmin(acc, v) : (acc + v);
    }
#pragma unroll
    for (int off = 32; off > 0; off >>= 1) {
      const double o = __shfl_xor(acc, off);
      acc = ismin ? fmin(acc, o) : (acc + o);
    }
    if (lane == 0) SCh[15] = acc;
  }
  hbar(bc, bt, lane);
  return SCh[15];
}

// stage 64 columns of RAW transformed train rows into GBUF[25][68].
// CHW=64 is LOAD-BEARING: 128-wide staging (R3/R4/R6) blows the VGPR
// budget via the unrolled float4 Gram loop -> hv spills to scratch ->
// ~600 MB HBM traffic and 2.2x slowdown.
__device__ __forceinline__ void stage_chunk(const float* __restrict__ tb,
                                            const int ch, const bool us,
                                            const float Cg, float* GBUF,
                                            const int tl) {
  for (int idx = tl; idx < 1600; idx += 320) {
    const int r = idx >> 6, cc = idx & 63;
    float v = tb[r * DF + (ch << 6) + cc];
    if (us) v = simple_tf(v, Cg);
    GBUF[r * 68 + cc] = v;
  }
}

// =====================================================================
// qp_kernel: TWO batches per 640-thread block (waves 0-4 / 5-9), grid
// B/2 = 256 -> exactly 1 block/CU, 10 waves resident (PROVEN shape).
// SINGLE delta vs R5 (441.9us best): all intra-QP sync is per-half
// hbar instead of block-wide __syncthreads (A/B test of the lockstep
// theory). Everything else byte-identical to R5.
// =====================================================================
__global__ void __launch_bounds__(TPB) qp_kernel(
    const float* __restrict__ train, const int* __restrict__ usimple,
    float* __restrict__ xfg, const int B) {
  const int tid = threadIdx.x;
  const int half = tid >= 320 ? 1 : 0;
  const int tl = tid - 320 * half;
  const int lane = tid & 63;
  const int w = tl >> 6;
  const int bb = 2 * blockIdx.x + half;
  const bool live = bb < B;
  const bool us = (usimple[0] != 0);
  const float Cg = gfun(1e-5f);

  __shared__ double Msh_[2][650];
  __shared__ __align__(16) unsigned char GBW_[2][6800];
  __shared__ double x_[2][125], s_[2][125], z_[2][125], rx_[2][125],
      rz_[2][125], dd_[2][125], di_[2][125], tt_[2][125], c1_[2][125],
      vv_[2][125], dxa_[2][125], dsa_[2][125], dza_[2][125], rsc_[2][125];
  __shared__ double yv_[2][25], ry_[2][25], c2_[2][25], gg_[2][25],
      dya_[2][25], dyw_[2][25];
  __shared__ double SC_[2][16];
  __shared__ float invn_[2][25];
  __shared__ float bxs_[2][125];
  __shared__ unsigned bctr[2];

  double* Msh = Msh_[half];
  double* W = (double*)GBW_[half];
  float* GBUF = (float*)GBW_[half];
  double* x = x_[half];
  double* sv = s_[half];
  double* zv = z_[half];
  double* rx = rx_[half];
  double* rz = rz_[half];
  double* dd = dd_[half];
  double* di = di_[half];
  double* tt = tt_[half];
  double* c1 = c1_[half];
  double* vv = vv_[half];
  double* dxa = dxa_[half];
  double* dsa = dsa_[half];
  double* dza = dza_[half];
  double* rsc = rsc_[half];
  double* yv = yv_[half];
  double* ry = ry_[half];
  double* c2 = c2_[half];
  double* gg = gg_[half];
  double* dya = dya_[half];
  double* dyw = dyw_[half];
  double* SC = SC_[half];
  float* invn = invn_[half];
  float* bxs = bxs_[half];
  double* dinvn = c2;  // c2 is dead until the first kkt_solve
  double hv[25];
  unsigned* bc = &bctr[half];
  unsigned bt = 0;

  if (tid < 2) bctr[tid] = 0;
  __syncthreads();  // the ONLY block-wide barrier

  const float* tb = train + (size_t)(live ? bb : 0) * NSUP * DF;

  // ---- phase 2: chunked RAW Gram G = F F^T (fp64 accumulate) ----
  int i1, j1, i2v = 0, j2v = 0;
  {
    int rem = tl, i = 0;
    while (rem >= NSUP - i) { rem -= NSUP - i; ++i; }
    i1 = i; j1 = i + rem;
  }
  if (tl < 5) {
    int rem = 320 + tl, i = 0;
    while (rem >= NSUP - i) { rem -= NSUP - i; ++i; }
    i2v = i; j2v = i + rem;
  }
  double acc1 = 0.0, acc2 = 0.0;
  for (int ch = 0; ch < 10; ++ch) {
    stage_chunk(tb, ch, us, Cg, GBUF, tl);
    hbar(bc, bt, lane);
    {
      const float4* ra = (const float4*)(GBUF + i1 * 68);
      const float4* rb = (const float4*)(GBUF + j1 * 68);
#pragma unroll
      for (int c = 0; c < 16; ++c) {
        float4 av = ra[c], bv = rb[c];
        acc1 += (double)av.x * bv.x + (double)av.y * bv.y +
                (double)av.z * bv.z + (double)av.w * bv.w;
      }
    }
    if (tl < 5) {
      const float4* ra = (const float4*)(GBUF + i2v * 68);
      const float4* rb = (const float4*)(GBUF + j2v * 68);
#pragma unroll
      for (int c = 0; c < 16; ++c) {
        float4 av = ra[c], bv = rb[c];
        acc2 += (double)av.x * bv.x + (double)av.y * bv.y +
                (double)av.z * bv.z + (double)av.w * bv.w;
      }
    }
    hbar(bc, bt, lane);
  }
  Msh[i1 * 26 + j1] = acc1;
  if (i1 != j1) Msh[j1 * 26 + i1] = acc1;
  if (tl < 5) {
    Msh[i2v * 26 + j2v] = acc2;
    if (i2v != j2v) Msh[j2v * 26 + i2v] = acc2;
  }
  hbar(bc, bt, lane);

  // ---- norms from Gram diagonal; rescale M = D G D + I ----
  if (tl < 25) {
    const double g = Msh[tl * 27];
    const double dn = 1.0 / fmax(sqrt(g), 1e-12);
    dinvn[tl] = dn;
    invn[tl] = (float)dn;
  }
  hbar(bc, bt, lane);
  for (int idx = tl; idx < 650; idx += 320) {
    const int i = idx / 26, j = idx - i * 26;
    if (j < 25) {
      double v = Msh[idx] * dinvn[i] * dinvn[j];
      if (i == j) v += 1.0;
      Msh[idx] = v;
    }
  }

  // ---- phase 3: QP init ----
  if (tl < NZV) {
    const int i = tl / 5, k = tl - i * 5;
    const double oh = (k == (i % 5)) ? 1.0 : 0.0;
    rx[tl] = -oh;
    rz[tl] = -0.1 * oh;
    dd[tl] = 1.0;
    di[tl] = 1.0;
  } else if (tl >= 128 && tl < 153) {
    ry[tl - 128] = 0.0;
  }
  if (tl == 0) SC[0] = 1e300;
  hbar(bc, bt, lane);

  factorize(Msh, dd, W, hv, tl, lane, w, bc, bt);
  kkt_solve<true, false, false>(Msh, dd, di, tt, c1, c2, vv, gg, dyw, rx,
                                (const double*)nullptr, rz, ry, hv, x, sv, zv,
                                yv, tl, lane, w, bc, bt);
  {
    const double ms = bred(sv, NZV, 1, SC, w, lane, bc, bt);
    if (ms < 0.0 && tl < NZV) sv[tl] -= (ms - 1.0);
    const double mz = bred(zv, NZV, 1, SC, w, lane, bc, bt);
    if (mz < 0.0 && tl < NZV) zv[tl] -= (mz - 1.0);
  }
  if (tl < NZV) bxs[tl] = (float)x[tl];

#pragma unroll 1
  for (int it = 0; it < 3; ++it) {
    hbar(bc, bt, lane);
    if (tl < NZV) {
      const int i = tl / 5, k = tl - i * 5;
      double acc = 0.0;
#pragma unroll
      for (int j = 0; j < 25; ++j) acc += Msh[i * 26 + j] * x[j * 5 + k];
      const double oh = (k == (i % 5)) ? 1.0 : 0.0;
      rx[tl] = yv[i] + zv[tl] + acc - oh;
      rz[tl] = x[tl] + sv[tl] - 0.1 * oh;
    } else if (tl >= 128 && tl < 153) {
      const int i = tl - 128;
      double acc = 0.0;
#pragma unroll
      for (int k = 0; k < 5; ++k) acc += x[i * 5 + k];
      ry[i] = acc;
    }
    hbar(bc, bt, lane);
    if (w == 0) {  // per-half consolidated 4-sum reduction (first wave)
      double s1 = 0, s2 = 0, s3 = 0, s4 = 0;
      for (int m = lane; m < 125; m += 64) {
        s1 += sv[m] * zv[m];
        s2 += rx[m] * rx[m];
        s3 += rz[m] * rz[m];
      }
      if (lane < 25) s4 = ry[lane] * ry[lane];
#pragma unroll
      for (int off = 32; off > 0; off >>= 1) {
        s1 += __shfl_xor(s1, off);
        s2 += __shfl_xor(s2, off);
        s3 += __shfl_xor(s3, off);
        s4 += __shfl_xor(s4, off);
      }
      if (lane == 0) { SC[2] = s1; SC[3] = s2; SC[4] = s3; SC[5] = s4; }
    }
    hbar(bc, bt, lane);
    const double szsum = SC[2];
    const double mu = fabs(szsum) / 125.0;
    const double res = sqrt(SC[4] + 1e-30) + sqrt(SC[5] + 1e-30) +
                       sqrt(SC[3] + 1e-30) + 125.0 * mu;
    if (tl == 0) {
      if (res < SC[0]) { SC[0] = res; SC[1] = 1.0; } else SC[1] = 0.0;
    }
    hbar(bc, bt, lane);
    if (SC[1] != 0.0 && tl < NZV) bxs[tl] = (float)x[tl];
    if (it == 2) break;
    hbar(bc, bt, lane);

    if (tl < NZV) {
      dd[tl] = zv[tl] * fdrcp(sv[tl]);
      di[tl] = sv[tl] * fdrcp(zv[tl]);
    }
    hbar(bc, bt, lane);
    factorize(Msh, dd, W, hv, tl, lane, w, bc, bt);
    kkt_solve<false, false, false>(Msh, dd, di, tt, c1, c2, vv, gg, dyw, rx,
                                   zv, rz, ry, hv, dxa, dsa, dza, dya, tl,
                                   lane, w, bc, bt);
    if (tl < NZV) {
      const double a1 = (dza[tl] < 0.0) ? (-zv[tl] / dza[tl]) : 1e12;
      const double a2 = (dsa[tl] < 0.0) ? (-sv[tl] / dsa[tl]) : 1e12;
      tt[tl] = fmin(a1, a2);
    }
    const double aff = fmin(bred(tt, NZV, 1, SC, w, lane, bc, bt), 1.0);
    if (tl < NZV)
      tt[tl] = (sv[tl] + aff * dsa[tl]) * (zv[tl] + aff * dza[tl]);
    const double num = bred(tt, NZV, 0, SC, w, lane, bc, bt);
    const double sg = num / szsum;
    const double musig = mu * (sg * sg * sg);
    if (tl < NZV) rsc[tl] = (-musig + dsa[tl] * dza[tl]) * fdrcp(sv[tl]);
    hbar(bc, bt, lane);
    kkt_solve<false, true, true>(Msh, dd, di, tt, c1, c2, vv, gg, dyw, rx,
                                 rsc, rz, ry, hv, dxa, dsa, dza, dya, tl,
                                 lane, w, bc, bt);
    if (tl < NZV) {
      const double a1 = (dza[tl] < 0.0) ? (-zv[tl] / dza[tl]) : 1e12;
      const double a2 = (dsa[tl] < 0.0) ? (-sv[tl] / dsa[tl]) : 1e12;
      tt[tl] = fmin(a1, a2);
    }
    const double al = fmin(0.999 * bred(tt, NZV, 1, SC, w, lane, bc, bt),
                           1.0);
    if (tl < NZV) {
      x[tl] += al * dxa[tl];
      sv[tl] += al * dsa[tl];
      zv[tl] += al * dza[tl];
    } else if (tl >= 128 && tl < 153) {
      const int i = tl - 128;
      yv[i] += al * dya[i];
    }
  }
  hbar(bc, bt, lane);

  // ---- phase 4: xfg[w][d] = sum_s (bx[s,w]*invn[s]) * Fraw[s][d] ----
  float xs[25];
#pragma unroll
  for (int s_ = 0; s_ < 25; ++s_) xs[s_] = bxs[s_ * 5 + w] * invn[s_];
  for (int ch = 0; ch < 10; ++ch) {
    stage_chunk(tb, ch, us, Cg, GBUF, tl);
    hbar(bc, bt, lane);
    float acc = 0.0f;
#pragma unroll
    for (int s_ = 0; s_ < 25; ++s_) acc += xs[s_] * GBUF[s_ * 68 + lane];
    if (live)
      xfg[((size_t)bb * NWAY + w) * DF + (ch << 6) + lane] = acc;
    hbar(bc, bt, lane);
  }
}

// =====================================================================
// Output kernel: TWO blocks per batch (even/odd queries), grid 2B,
// small LDS (12.8 KB) so blocks co-reside. float4 loads (3/query).
// Unchanged from R5.
// =====================================================================
__global__ void __launch_bounds__(640) out_kernel(
    const float* __restrict__ test, const int* __restrict__ usimple,
    const float* __restrict__ xfg, float* __restrict__ out) {
  const int bid = blockIdx.x;
  const int b = bid >> 1;
  const int hh = bid & 1;   // even / odd queries
  const int tid = threadIdx.x;
  const int lane = tid & 63;
  const int u = tid >> 6;   // 0..9
  const bool us = (usimple[0] != 0);
  const float Cg = gfun(1e-5f);

  __shared__ float xfs[NWAY * DF];
  for (int i = tid; i < NWAY * DF; i += 640)
    xfs[i] = xfg[(size_t)b * NWAY * DF + i];
  __syncthreads();
  const float4* xf4 = (const float4*)xfs;

  const float* qb = test + (size_t)b * NQ * DF;
#pragma unroll 2
  for (int jj = 0; jj < 4; ++jj) {
    const int q = 2 * (u + 10 * jj) + hh;
    if (q >= NQ) break;  // q monotone in jj
    const float4* qr4 = (const float4*)(qb + (size_t)q * DF);
    float nrm = 0.0f, a0 = 0.0f, a1 = 0.0f, a2 = 0.0f, a3 = 0.0f, a4 = 0.0f;
#pragma unroll
    for (int c = 0; c < 3; ++c) {
      if (c < 2 || lane < 32) {
        const int f4i = lane + 64 * c;
        float4 vq = qr4[f4i];
        if (us) {
          vq.x = simple_tf(vq.x, Cg);
          vq.y = simple_tf(vq.y, Cg);
          vq.z = simple_tf(vq.z, Cg);
          vq.w = simple_tf(vq.w, Cg);
        }
        nrm += vq.x * vq.x + vq.y * vq.y + vq.z * vq.z + vq.w * vq.w;
        float4 t;
        t = xf4[0 * (DF / 4) + f4i];
        a0 += vq.x * t.x + vq.y * t.y + vq.z * t.z + vq.w * t.w;
        t = xf4[1 * (DF / 4) + f4i];
        a1 += vq.x * t.x + vq.y * t.y + vq.z * t.z + vq.w * t.w;
        t = xf4[2 * (DF / 4) + f4i];
        a2 += vq.x * t.x + vq.y * t.y + vq.z * t.z + vq.w * t.w;
        t = xf4[3 * (DF / 4) + f4i];
        a3 += vq.x * t.x + vq.y * t.y + vq.z * t.z + vq.w * t.w;
        t = xf4[4 * (DF / 4) + f4i];
        a4 += vq.x * t.x + vq.y * t.y + vq.z * t.z + vq.w * t.w;
      }
    }
#pragma unroll
    for (int off = 32; off > 0; off >>= 1) {
      nrm += __shfl_xor(nrm, off);
      a0 += __shfl_xor(a0, off);
      a1 += __shfl_xor(a1, off);
      a2 += __shfl_xor(a2, off);
      a3 += __shfl_xor(a3, off);
      a4 += __shfl_xor(a4, off);
    }
    if (lane == 0) {
      const float sc = 1.0f / fmaxf(sqrtf(nrm), 1e-12f);
      float* op = out + ((size_t)b * NQ + q) * 5;
      op[0] = a0 * sc;
      op[1] = a1 * sc;
      op[2] = a2 * sc;
      op[3] = a3 * sc;
      op[4] = a4 * sc;
    }
  }
}

// =====================================================================
extern "C" void kernel_launch(void* const* d_in, const int* in_sizes, int n_in,
                              void* d_out, int out_size, void* d_ws,
                              size_t ws_size, hipStream_t stream) {
  const float* ftest = (const float*)d_in[0];
  const float* ftrain = (const float*)d_in[1];
  const int* usimple = (const int*)d_in[4];
  float* out = (float*)d_out;
  const int B = in_sizes[1] / (NSUP * DF);

  float* xfg = (float*)d_ws;  // B * 5 * 640 floats

  qp_kernel<<<dim3((B + 1) / 2), dim3(TPB), 0, stream>>>(ftrain, usimple,
                                                         xfg, B);
  out_kernel<<<dim3(2 * B), dim3(640), 0, stream>>>(ftest, usimple, xfg,
                                                    out);
}

// Round 9
// 352.407 us; speedup vs baseline: 1.9748x; 1.9748x over previous
//
#include <hip/hip_runtime.h>
#include <math.h>

#define NWAY 5
#define NSUP 25
#define NZV  125
#define DF   640
#define NQ   75
#define TPB  640   // two batches per block: waves 0-4 batch A, 5-9 batch B

// =====================================================================
// Fast transform: tf(x) = sign(x) * (g(|x|+1e-5) - g(1e-5)),
//   g(t) = ln(1/t+1)^{-1.3} = exp2(-1.3*log2(log2(1/t+1)) + A),
//   A = -1.3*log2(ln2) = 0.68739628. 4 transcendentals vs reference's 8.
// =====================================================================
__device__ __forceinline__ float gfun(float t) {
  const float l2 = __log2f(__builtin_amdgcn_rcpf(t) + 1.0f);
  return __builtin_amdgcn_exp2f(fmaf(-1.3f, __log2f(l2), 0.68739628f));
}
__device__ __forceinline__ float simple_tf(float x, float Cg) {
  const float s = gfun(fabsf(x) + 1e-5f) - Cg;
  return (x >= 0.0f) ? s : -s;
}

// Fast fp32 reciprocal: v_rcp_f32 + 1 Newton -> full f32 accuracy.
// Inputs strictly positive (SPD pivots, s, z).
__device__ __forceinline__ float frcp_nr(float d) {
  float r = __builtin_amdgcn_rcpf(d);
  r = r * fmaf(-d, r, 2.0f);
  return r;
}

// Constant-lane f32 broadcast via v_readlane (single op; off the LDS pipe).
__device__ __forceinline__ float bcastf(float v, const int srclane) {
  return __int_as_float(
      __builtin_amdgcn_readlane(__float_as_int(v), srclane));
}

// In-place Gauss-Jordan of 25x25 SPD (fp32); columns on lanes BASE..BASE+24.
// M = normalized Gram + I (+dd): eigenvalues in [1, 26+max dd] -> well
// conditioned; GJ without pivoting on SPD is stable in f32.
template <int BASE, int J>
__device__ __forceinline__ void gjp(float (&a)[25], const int lane,
                                    const bool act) {
  const float djj = bcastf(a[J], BASE + J);
  const float pinv = frcp_nr(djj);
  if (act) a[J] = ((lane == BASE + J) ? 1.0f : a[J]) * pinv;
#pragma unroll
  for (int r = 0; r < 25; ++r) {
    if (r != J) {
      const float f = bcastf(a[r], BASE + J);
      if (act) a[r] = ((lane == BASE + J) ? 0.0f : a[r]) - f * a[J];
    }
  }
}
template <int BASE, int J = 0>
__device__ __forceinline__ void gjall(float (&a)[25], const int lane,
                                      const bool act) {
  if constexpr (J < 25) {
    gjp<BASE, J>(a, lane, act);
    gjall<BASE, J + 1>(a, lane, act);
  }
}

// Factorize (per half): hv <- row `lane` of Hinv_w; this half's wave-0
// lanes 32-56 additionally get Winv = (sum_k Hinv_k)^-1 rows.
// W accumulation: write-first sequential waves (R5 scheme; atomics,
// flag barriers and Hs-dump variants all measured-negative R2/R7/R8).
__device__ __forceinline__ void factorize(const float* Msh, const float* dd,
                                          float* W, float (&hv)[25],
                                          const int tl, const int lane,
                                          const int w) {
  if (lane < 25) {
#pragma unroll
    for (int j = 0; j < 25; ++j)
      hv[j] = Msh[lane * 26 + j] + ((j == lane) ? dd[lane * 5 + w] : 0.0f);
  }
  gjall<0>(hv, lane, true);
#pragma unroll
  for (int k = 0; k < 5; ++k) {
    if (w == k && lane < 25) {
      if (k == 0) {
#pragma unroll
        for (int j = 0; j < 25; ++j) W[lane * 26 + j] = hv[j];
      } else {
#pragma unroll
        for (int j = 0; j < 25; ++j) W[lane * 26 + j] += hv[j];
      }
    }
    __syncthreads();
  }
  if (w == 0) {
    if (lane >= 32 && lane < 57) {
#pragma unroll
      for (int r = 0; r < 25; ++r) hv[r] = W[(lane - 32) * 26 + r];
    }
    gjall<32>(hv, lane, lane >= 32 && lane < 57);
  }
  // next consumer phase begins with its own __syncthreads()
}

// KKT solve (per half), fp32. ZRS: rs==0; ZR: rx=rz=ry==0; ACC: accumulate.
// di = 1/dd precomputed -> the two per-solve divides become multiplies.
template <bool ZRS, bool ZR, bool ACC>
__device__ __forceinline__ void kkt_solve(
    const float* Msh, const float* dd, const float* di, float* tt,
    float* c1, float* c2, float* vv, float* gg, float* dyw,
    const float* rx, const float* rs, const float* rz, const float* ry,
    float (&hv)[25], float* dx, float* ds, float* dz, float* dy,
    const int tl, const int lane, const int w) {
  if (tl < NZV) {
    float t = ZR ? 0.0f : rz[tl];
    if (!ZRS) t -= rs[tl] * di[tl];
    tt[tl] = t;
  }
  __syncthreads();
  if (tl < NZV) {
    const int i = tl / 5, k = tl - i * 5;
    float acc = ZR ? 0.0f : -rx[tl];
#pragma unroll
    for (int j = 0; j < 25; ++j) acc += Msh[i * 26 + j] * tt[j * 5 + k];
    c1[tl] = acc;
  } else if (tl >= 128 && tl < 153) {
    const int i = tl - 128;
    float acc = ZR ? 0.0f : -ry[i];
#pragma unroll
    for (int k = 0; k < 5; ++k) acc += tt[i * 5 + k];
    c2[i] = acc;
  }
  __syncthreads();
  if (lane < 25) {
    float acc = 0.0f;
#pragma unroll
    for (int j = 0; j < 25; ++j) acc += hv[j] * c1[j * 5 + w];
    vv[lane * 5 + w] = acc;
  }
  __syncthreads();
  if (w == 0) {  // gg then dy in the SAME wave: LDS program order suffices
    if (lane < 25) {
      float acc = -c2[lane];
#pragma unroll
      for (int k = 0; k < 5; ++k) acc += vv[lane * 5 + k];
      gg[lane] = acc;
    }
    if (lane >= 32 && lane < 57) {
      float acc = 0.0f;
#pragma unroll
      for (int r = 0; r < 25; ++r) acc += hv[r] * gg[r];
      dyw[lane - 32] = acc;
      if (ACC) dy[lane - 32] += acc; else dy[lane - 32] = acc;
    }
  }
  __syncthreads();
  if (lane < 25) {
    float acc = 0.0f;
#pragma unroll
    for (int j = 0; j < 25; ++j) acc += hv[j] * dyw[j];
    const int v = lane * 5 + w;
    const float u = vv[v] - acc;
    const float dzv = dd[v] * u;
    const float dxv = u - tt[v];
    const float dsv = ((ZRS ? 0.0f : -rs[v]) - dzv) * di[v];
    if (ACC) { dz[v] += dzv; dx[v] += dxv; ds[v] += dsv; }
    else     { dz[v]  = dzv; dx[v]  = dxv; ds[v]  = dsv; }
  }
  __syncthreads();
}

// Per-half block reduction: first wave of the half reduces buf[0..n).
__device__ __forceinline__ float bred(const float* buf, int n, int ismin,
                                      float* SCh, const int w,
                                      const int lane) {
  __syncthreads();
  if (w == 0) {
    float acc = ismin ? 1e30f : 0.0f;
    for (int m = lane; m < n; m += 64) {
      const float v = buf[m];
      acc = ismin ? fminf(acc, v) : (acc + v);
    }
#pragma unroll
    for (int off = 32; off > 0; off >>= 1) {
      const float o = __shfl_xor(acc, off);
      acc = ismin ? fminf(acc, o) : (acc + o);
    }
    if (lane == 0) SCh[15] = acc;
  }
  __syncthreads();
  return SCh[15];
}

// stage 64 columns of RAW transformed train rows into GBUF[25][68].
// CHW=64 is LOAD-BEARING (wider staging spills hv -> 600 MB HBM, 2.2x).
__device__ __forceinline__ void stage_chunk(const float* __restrict__ tb,
                                            const int ch, const bool us,
                                            const float Cg, float* GBUF,
                                            const int tl) {
  for (int idx = tl; idx < 1600; idx += 320) {
    const int r = idx >> 6, cc = idx & 63;
    float v = tb[r * DF + (ch << 6) + cc];
    if (us) v = simple_tf(v, Cg);
    GBUF[r * 68 + cc] = v;
  }
}

// =====================================================================
// qp_kernel: TWO batches per 640-thread block (waves 0-4 / 5-9), grid
// B/2 = 256 -> 1 block/CU, 10 waves resident (PROVEN R5 shape; every
// structural variant regressed). SINGLE delta vs R5 (441.9us): the QP
// core runs in FP32 (reference is JAX f32; our fp64 was surplus).
// Gram stays fp64-accumulated in registers -> f64 scratch -> M cast to
// f32 once. Halves LDS bytes/phase, VALU issue, broadcast count, and
// shortens every dependent chain (f32 rcp+1NR vs f64 rcp+2NR).
// =====================================================================
__global__ void __launch_bounds__(TPB) qp_kernel(
    const float* __restrict__ train, const int* __restrict__ usimple,
    float* __restrict__ xfg, const int B) {
  const int tid = threadIdx.x;
  const int half = tid >= 320 ? 1 : 0;
  const int tl = tid - 320 * half;
  const int lane = tid & 63;
  const int w = tl >> 6;
  const int bb = 2 * blockIdx.x + half;
  const bool live = bb < B;
  const bool us = (usimple[0] != 0);
  const float Cg = gfun(1e-5f);

  __shared__ float Msh_[2][650];
  // union: Gd (650 f64, Gram result) / W (650 f32, factorize) / GBUF
  // (1700 f32, staging) -- all temporally disjoint.
  __shared__ __align__(16) unsigned char GBW_[2][6800];
  __shared__ float x_[2][125], s_[2][125], z_[2][125], rx_[2][125],
      rz_[2][125], dd_[2][125], di_[2][125], tt_[2][125], c1_[2][125],
      vv_[2][125], dxa_[2][125], dsa_[2][125], dza_[2][125], rsc_[2][125];
  __shared__ float yv_[2][25], ry_[2][25], c2_[2][25], gg_[2][25],
      dya_[2][25], dyw_[2][25];
  __shared__ float SC_[2][16];
  __shared__ double dnv_[2][25];
  __shared__ float invn_[2][25];
  __shared__ float bxs_[2][125];

  float* Msh = Msh_[half];
  double* Gd = (double*)GBW_[half];   // Gram result (fp64), pre-QP only
  float* W = (float*)GBW_[half];      // factorize only
  float* GBUF = (float*)GBW_[half];   // staging only
  float* x = x_[half];
  float* sv = s_[half];
  float* zv = z_[half];
  float* rx = rx_[half];
  float* rz = rz_[half];
  float* dd = dd_[half];
  float* di = di_[half];
  float* tt = tt_[half];
  float* c1 = c1_[half];
  float* vv = vv_[half];
  float* dxa = dxa_[half];
  float* dsa = dsa_[half];
  float* dza = dza_[half];
  float* rsc = rsc_[half];
  float* yv = yv_[half];
  float* ry = ry_[half];
  float* c2 = c2_[half];
  float* gg = gg_[half];
  float* dya = dya_[half];
  float* dyw = dyw_[half];
  float* SC = SC_[half];
  double* dnv = dnv_[half];
  float* invn = invn_[half];
  float* bxs = bxs_[half];
  float hv[25];

  const float* tb = train + (size_t)(live ? bb : 0) * NSUP * DF;

  // ---- phase 2: chunked RAW Gram G = F F^T (fp64 register accum) ----
  int i1, j1, i2v = 0, j2v = 0;
  {
    int rem = tl, i = 0;
    while (rem >= NSUP - i) { rem -= NSUP - i; ++i; }
    i1 = i; j1 = i + rem;
  }
  if (tl < 5) {
    int rem = 320 + tl, i = 0;
    while (rem >= NSUP - i) { rem -= NSUP - i; ++i; }
    i2v = i; j2v = i + rem;
  }
  double acc1 = 0.0, acc2 = 0.0;
  for (int ch = 0; ch < 10; ++ch) {
    stage_chunk(tb, ch, us, Cg, GBUF, tl);
    __syncthreads();
    {
      const float4* ra = (const float4*)(GBUF + i1 * 68);
      const float4* rb = (const float4*)(GBUF + j1 * 68);
#pragma unroll
      for (int c = 0; c < 16; ++c) {
        float4 av = ra[c], bv = rb[c];
        acc1 += (double)av.x * bv.x + (double)av.y * bv.y +
                (double)av.z * bv.z + (double)av.w * bv.w;
      }
    }
    if (tl < 5) {
      const float4* ra = (const float4*)(GBUF + i2v * 68);
      const float4* rb = (const float4*)(GBUF + j2v * 68);
#pragma unroll
      for (int c = 0; c < 16; ++c) {
        float4 av = ra[c], bv = rb[c];
        acc2 += (double)av.x * bv.x + (double)av.y * bv.y +
                (double)av.z * bv.z + (double)av.w * bv.w;
      }
    }
    __syncthreads();
  }
  // GBUF is dead; store fp64 Gram into the same union region.
  Gd[i1 * 26 + j1] = acc1;
  if (i1 != j1) Gd[j1 * 26 + i1] = acc1;
  if (tl < 5) {
    Gd[i2v * 26 + j2v] = acc2;
    if (i2v != j2v) Gd[j2v * 26 + i2v] = acc2;
  }
  __syncthreads();

  // ---- norms from Gram diagonal (fp64); M = f32(D G D) + I ----
  if (tl < 25) {
    const double g = Gd[tl * 27];
    const double dn = 1.0 / fmax(sqrt(g), 1e-12);
    dnv[tl] = dn;
    invn[tl] = (float)dn;
  }
  __syncthreads();
  for (int idx = tl; idx < 650; idx += 320) {
    const int i = idx / 26, j = idx - i * 26;
    if (j < 25) {
      float v = (float)(Gd[idx] * dnv[i] * dnv[j]);
      if (i == j) v += 1.0f;
      Msh[idx] = v;
    }
  }

  // ---- phase 3: QP init ----
  if (tl < NZV) {
    const int i = tl / 5, k = tl - i * 5;
    const float oh = (k == (i % 5)) ? 1.0f : 0.0f;
    rx[tl] = -oh;
    rz[tl] = -0.1f * oh;
    dd[tl] = 1.0f;
    di[tl] = 1.0f;
  } else if (tl >= 128 && tl < 153) {
    ry[tl - 128] = 0.0f;
  }
  if (tl == 0) SC[0] = 1e30f;
  __syncthreads();

  factorize(Msh, dd, W, hv, tl, lane, w);
  kkt_solve<true, false, false>(Msh, dd, di, tt, c1, c2, vv, gg, dyw, rx,
                                (const float*)nullptr, rz, ry, hv, x, sv, zv,
                                yv, tl, lane, w);
  {
    const float ms = bred(sv, NZV, 1, SC, w, lane);
    if (ms < 0.0f && tl < NZV) sv[tl] -= (ms - 1.0f);
    const float mz = bred(zv, NZV, 1, SC, w, lane);
    if (mz < 0.0f && tl < NZV) zv[tl] -= (mz - 1.0f);
  }
  if (tl < NZV) bxs[tl] = x[tl];

#pragma unroll 1
  for (int it = 0; it < 3; ++it) {
    __syncthreads();
    if (tl < NZV) {
      const int i = tl / 5, k = tl - i * 5;
      float acc = 0.0f;
#pragma unroll
      for (int j = 0; j < 25; ++j) acc += Msh[i * 26 + j] * x[j * 5 + k];
      const float oh = (k == (i % 5)) ? 1.0f : 0.0f;
      rx[tl] = yv[i] + zv[tl] + acc - oh;
      rz[tl] = x[tl] + sv[tl] - 0.1f * oh;
    } else if (tl >= 128 && tl < 153) {
      const int i = tl - 128;
      float acc = 0.0f;
#pragma unroll
      for (int k = 0; k < 5; ++k) acc += x[i * 5 + k];
      ry[i] = acc;
    }
    __syncthreads();
    if (w == 0) {  // per-half consolidated 4-sum reduction (first wave)
      float s1 = 0, s2 = 0, s3 = 0, s4 = 0;
      for (int m = lane; m < 125; m += 64) {
        s1 += sv[m] * zv[m];
        s2 += rx[m] * rx[m];
        s3 += rz[m] * rz[m];
      }
      if (lane < 25) s4 = ry[lane] * ry[lane];
#pragma unroll
      for (int off = 32; off > 0; off >>= 1) {
        s1 += __shfl_xor(s1, off);
        s2 += __shfl_xor(s2, off);
        s3 += __shfl_xor(s3, off);
        s4 += __shfl_xor(s4, off);
      }
      if (lane == 0) { SC[2] = s1; SC[3] = s2; SC[4] = s3; SC[5] = s4; }
    }
    __syncthreads();
    const float szsum = SC[2];
    const float mu = fabsf(szsum) / 125.0f;
    const float res = sqrtf(SC[4] + 1e-30f) + sqrtf(SC[5] + 1e-30f) +
                      sqrtf(SC[3] + 1e-30f) + 125.0f * mu;
    if (tl == 0) {
      if (res < SC[0]) { SC[0] = res; SC[1] = 1.0f; } else SC[1] = 0.0f;
    }
    __syncthreads();
    if (SC[1] != 0.0f && tl < NZV) bxs[tl] = x[tl];
    if (it == 2) break;
    __syncthreads();

    if (tl < NZV) {
      dd[tl] = zv[tl] * frcp_nr(sv[tl]);
      di[tl] = sv[tl] * frcp_nr(zv[tl]);
    }
    __syncthreads();
    factorize(Msh, dd, W, hv, tl, lane, w);
    kkt_solve<false, false, false>(Msh, dd, di, tt, c1, c2, vv, gg, dyw, rx,
                                   zv, rz, ry, hv, dxa, dsa, dza, dya, tl,
                                   lane, w);
    if (tl < NZV) {
      const float a1 = (dza[tl] < 0.0f) ? (-zv[tl] / dza[tl]) : 1e12f;
      const float a2 = (dsa[tl] < 0.0f) ? (-sv[tl] / dsa[tl]) : 1e12f;
      tt[tl] = fminf(a1, a2);
    }
    const float aff = fminf(bred(tt, NZV, 1, SC, w, lane), 1.0f);
    if (tl < NZV)
      tt[tl] = (sv[tl] + aff * dsa[tl]) * (zv[tl] + aff * dza[tl]);
    const float num = bred(tt, NZV, 0, SC, w, lane);
    const float sg = num / szsum;
    const float musig = mu * (sg * sg * sg);
    if (tl < NZV) rsc[tl] = (-musig + dsa[tl] * dza[tl]) * frcp_nr(sv[tl]);
    __syncthreads();
    kkt_solve<false, true, true>(Msh, dd, di, tt, c1, c2, vv, gg, dyw, rx,
                                 rsc, rz, ry, hv, dxa, dsa, dza, dya, tl,
                                 lane, w);
    if (tl < NZV) {
      const float a1 = (dza[tl] < 0.0f) ? (-zv[tl] / dza[tl]) : 1e12f;
      const float a2 = (dsa[tl] < 0.0f) ? (-sv[tl] / dsa[tl]) : 1e12f;
      tt[tl] = fminf(a1, a2);
    }
    const float al = fminf(0.999f * bred(tt, NZV, 1, SC, w, lane), 1.0f);
    if (tl < NZV) {
      x[tl] += al * dxa[tl];
      sv[tl] += al * dsa[tl];
      zv[tl] += al * dza[tl];
    } else if (tl >= 128 && tl < 153) {
      const int i = tl - 128;
      yv[i] += al * dya[i];
    }
  }
  __syncthreads();

  // ---- phase 4: xfg[w][d] = sum_s (bx[s,w]*invn[s]) * Fraw[s][d] ----
  float xs[25];
#pragma unroll
  for (int s_ = 0; s_ < 25; ++s_) xs[s_] = bxs[s_ * 5 + w] * invn[s_];
  for (int ch = 0; ch < 10; ++ch) {
    stage_chunk(tb, ch, us, Cg, GBUF, tl);
    __syncthreads();
    float acc = 0.0f;
#pragma unroll
    for (int s_ = 0; s_ < 25; ++s_) acc += xs[s_] * GBUF[s_ * 68 + lane];
    if (live)
      xfg[((size_t)bb * NWAY + w) * DF + (ch << 6) + lane] = acc;
    __syncthreads();
  }
}

// =====================================================================
// Output kernel: TWO blocks per batch (even/odd queries), grid 2B,
// small LDS (12.8 KB) so blocks co-reside. float4 loads (3/query).
// Unchanged from R5.
// =====================================================================
__global__ void __launch_bounds__(640) out_kernel(
    const float* __restrict__ test, const int* __restrict__ usimple,
    const float* __restrict__ xfg, float* __restrict__ out) {
  const int bid = blockIdx.x;
  const int b = bid >> 1;
  const int hh = bid & 1;   // even / odd queries
  const int tid = threadIdx.x;
  const int lane = tid & 63;
  const int u = tid >> 6;   // 0..9
  const bool us = (usimple[0] != 0);
  const float Cg = gfun(1e-5f);

  __shared__ float xfs[NWAY * DF];
  for (int i = tid; i < NWAY * DF; i += 640)
    xfs[i] = xfg[(size_t)b * NWAY * DF + i];
  __syncthreads();
  const float4* xf4 = (const float4*)xfs;

  const float* qb = test + (size_t)b * NQ * DF;
#pragma unroll 2
  for (int jj = 0; jj < 4; ++jj) {
    const int q = 2 * (u + 10 * jj) + hh;
    if (q >= NQ) break;  // q monotone in jj
    const float4* qr4 = (const float4*)(qb + (size_t)q * DF);
    float nrm = 0.0f, a0 = 0.0f, a1 = 0.0f, a2 = 0.0f, a3 = 0.0f, a4 = 0.0f;
#pragma unroll
    for (int c = 0; c < 3; ++c) {
      if (c < 2 || lane < 32) {
        const int f4i = lane + 64 * c;
        float4 vq = qr4[f4i];
        if (us) {
          vq.x = simple_tf(vq.x, Cg);
          vq.y = simple_tf(vq.y, Cg);
          vq.z = simple_tf(vq.z, Cg);
          vq.w = simple_tf(vq.w, Cg);
        }
        nrm += vq.x * vq.x + vq.y * vq.y + vq.z * vq.z + vq.w * vq.w;
        float4 t;
        t = xf4[0 * (DF / 4) + f4i];
        a0 += vq.x * t.x + vq.y * t.y + vq.z * t.z + vq.w * t.w;
        t = xf4[1 * (DF / 4) + f4i];
        a1 += vq.x * t.x + vq.y * t.y + vq.z * t.z + vq.w * t.w;
        t = xf4[2 * (DF / 4) + f4i];
        a2 += vq.x * t.x + vq.y * t.y + vq.z * t.z + vq.w * t.w;
        t = xf4[3 * (DF / 4) + f4i];
        a3 += vq.x * t.x + vq.y * t.y + vq.z * t.z + vq.w * t.w;
        t = xf4[4 * (DF / 4) + f4i];
        a4 += vq.x * t.x + vq.y * t.y + vq.z * t.z + vq.w * t.w;
      }
    }
#pragma unroll
    for (int off = 32; off > 0; off >>= 1) {
      nrm += __shfl_xor(nrm, off);
      a0 += __shfl_xor(a0, off);
      a1 += __shfl_xor(a1, off);
      a2 += __shfl_xor(a2, off);
      a3 += __shfl_xor(a3, off);
      a4 += __shfl_xor(a4, off);
    }
    if (lane == 0) {
      const float sc = 1.0f / fmaxf(sqrtf(nrm), 1e-12f);
      float* op = out + ((size_t)b * NQ + q) * 5;
      op[0] = a0 * sc;
      op[1] = a1 * sc;
      op[2] = a2 * sc;
      op[3] = a3 * sc;
      op[4] = a4 * sc;
    }
  }
}

// =====================================================================
extern "C" void kernel_launch(void* const* d_in, const int* in_sizes, int n_in,
                              void* d_out, int out_size, void* d_ws,
                              size_t ws_size, hipStream_t stream) {
  const float* ftest = (const float*)d_in[0];
  const float* ftrain = (const float*)d_in[1];
  const int* usimple = (const int*)d_in[4];
  float* out = (float*)d_out;
  const int B = in_sizes[1] / (NSUP * DF);

  float* xfg = (float*)d_ws;  // B * 5 * 640 floats

  qp_kernel<<<dim3((B + 1) / 2), dim3(TPB), 0, stream>>>(ftrain, usimple,
                                                         xfg, B);
  out_kernel<<<dim3(2 * B), dim3(640), 0, stream>>>(ftest, usimple, xfg,
                                                    out);
}